// Round 8
// baseline (136.869 us; speedup 1.0000x reference)
//
#include <hip/hip_runtime.h>
#include <math.h>

#ifndef __has_builtin
#define __has_builtin(x) 0
#endif

#define BS 4
#define LQ 128
#define IMG 256
#define NPIX (IMG*IMG)
#define NQ 4
#define NSLICE 8
#define SLICE_PIX (NPIX/NSLICE)   // 8192
#define SLICE_U4 (SLICE_PIX/4)    // 2048
#define SLOTS 4
#define NBLK (BS*(LQ/NQ)*NSLICE)  // 1024

__device__ __forceinline__ unsigned sad3_u8(unsigned a, unsigned b) {
#if __has_builtin(__builtin_amdgcn_sad_u8)
    return __builtin_amdgcn_sad_u8(a, b, 0u);
#else
    unsigned zero = 0, d;
    asm("v_sad_u8 %0, %1, %2, %3" : "=v"(d) : "v"(a), "v"(b), "v"(zero));
    return d;
#endif
}

__device__ __forceinline__ unsigned pk255(float r, float g, float b) {
    return (unsigned)rintf(r * 255.0f)
         | ((unsigned)rintf(g * 255.0f) << 8)
         | ((unsigned)rintf(b * 255.0f) << 16);
}

__device__ __forceinline__ bool lessVI(float v1, int i1, float v2, int i2) {
    return (v1 < v2) || (v1 == v2 && i1 < i2);
}

#define CE8(WV, WI, a, c)                                                     \
    do {                                                                      \
        if (lessVI((WV)[c], (WI)[c], (WV)[a], (WI)[a])) {                     \
            float tv_ = (WV)[a]; (WV)[a] = (WV)[c]; (WV)[c] = tv_;            \
            int   ti_ = (WI)[a]; (WI)[a] = (WI)[c]; (WI)[c] = ti_;            \
        }                                                                     \
    } while (0)

// merge two sorted-ascending 8-lists -> sorted 8 smallest of 16 (static idx)
#define MERGE8(AV, AI, BV, BI, OV, OI)                                        \
    do {                                                                      \
        _Pragma("unroll")                                                     \
        for (int k_ = 0; k_ < 8; ++k_) {                                      \
            if (lessVI((AV)[k_], (AI)[k_], (BV)[7-k_], (BI)[7-k_])) {         \
                (OV)[k_] = (AV)[k_]; (OI)[k_] = (AI)[k_];                     \
            } else { (OV)[k_] = (BV)[7-k_]; (OI)[k_] = (BI)[7-k_]; }          \
        }                                                                     \
        CE8(OV, OI, 0, 4); CE8(OV, OI, 1, 5); CE8(OV, OI, 2, 6); CE8(OV, OI, 3, 7); \
        CE8(OV, OI, 0, 2); CE8(OV, OI, 1, 3); CE8(OV, OI, 4, 6); CE8(OV, OI, 5, 7); \
        CE8(OV, OI, 0, 1); CE8(OV, OI, 2, 3); CE8(OV, OI, 4, 5); CE8(OV, OI, 6, 7); \
    } while (0)

// 1024 blocks x 512 threads. Block = (batch b, query-quad qg, slice sl).
// 0: quantize own slice to u8-RGB u32 in LDS (32 KB); init slots to sentinel.
// A: integer tau = 8th-smallest of 1024 sampled u8 sads (exact over samples);
//    scan test sad <= tau+6 provably catches every fp32 top-8 pixel.
// B: LDS-resident branchless scan; hits (~0.15/thread/query) go to a private
//    4-slot LDS array via exec-masked ds_write; c>SLOTS sets overflow flag.
// C: fp32 exact recheck of slot entries (or full-slice rescan on overflow)
//    -> exact lexicographic wave top-8 -> ws.
// Ticket: last block merges 8 slice lists per query and computes the loss.
__global__ __launch_bounds__(512)
void fused_kernel(const float* __restrict__ pred,
                  const float* __restrict__ imgs,
                  float2* __restrict__ ws,
                  int* __restrict__ counter,
                  float* __restrict__ out) {
    __shared__ unsigned slice_px[SLICE_PIX];        // 32 KB
    __shared__ unsigned slots[NQ * 512 * SLOTS];    // 32 KB
    __shared__ float    pool[NQ][3];
    __shared__ unsigned tau8[8];
    __shared__ int      over[NQ];
    __shared__ float    mv[NQ][2][8];
    __shared__ int      mi[NQ][2][8];
    __shared__ int      lastflag;
    __shared__ float    red[512];

    const int bid = blockIdx.x;
    // XCD swizzle: 2 XCD slots per batch -> each XCD's L2 holds one f32 image.
    const int b  = (bid & 7) >> 1;
    const int u  = bid >> 3;
    const int sl = u & (NSLICE - 1);
    const int qg = (u >> 3) | ((bid & 1) << 4);     // [0,32)
    const int tid = threadIdx.x;
    const int qi = tid >> 7;                        // this thread's query [0,4)
    const int st = tid & 127;
    const int wid  = tid >> 6;
    const int lane = tid & 63;

    // pooled color (reshape quirk: flat row n = l*BS + b of preds(bs*L,2))
    const int l  = qg * NQ + qi;
    const int n  = l * BS + b;
    const int pb = n >> 7;
    const int pl = n & (LQ - 1);
    const float gx = pred[(pb * LQ + pl) * 8 + 0];
    const float gy = pred[(pb * LQ + pl) * 8 + 1];
    const int ix = (int)fminf(fmaxf(rintf(gx * 256.0f - 0.5f), 0.0f), 255.0f);
    const int iy = (int)fminf(fmaxf(rintf(gy * 256.0f - 0.5f), 0.0f), 255.0f);
    const float* img = imgs + b * 3 * NPIX;
    const int pc = iy * IMG + ix;
    const float c0 = img[pc];
    const float c1 = img[NPIX + pc];
    const float c2 = img[2 * NPIX + pc];
    if (st == 0) { pool[qi][0] = c0; pool[qi][1] = c1; pool[qi][2] = c2; }
    const unsigned Qme = pk255(c0, c1, c2);
    if (tid < NQ) over[tid] = 0;

    // ---- Phase 0: quantize slice into LDS; sentinel-init slots
    {
        const float4* f0 = (const float4*)img + sl * SLICE_U4;
        const float4* f1 = (const float4*)(img + NPIX) + sl * SLICE_U4;
        const float4* f2 = (const float4*)(img + 2 * NPIX) + sl * SLICE_U4;
#pragma unroll
        for (int it = 0; it < SLICE_U4 / 512; ++it) {
            const int idx = it * 512 + tid;
            const float4 g0 = f0[idx];
            const float4 g1 = f1[idx];
            const float4 g2 = f2[idx];
            uint4 U;
            U.x = pk255(g0.x, g1.x, g2.x);
            U.y = pk255(g0.y, g1.y, g2.y);
            U.z = pk255(g0.z, g1.z, g2.z);
            U.w = pk255(g0.w, g1.w, g2.w);
            ((uint4*)slice_px)[idx] = U;
        }
#pragma unroll
        for (int k = 0; k < 16; ++k) slots[tid * 16 + k] = 0xFFFFFFFFu;
    }
    __syncthreads();

    // ---- Phase A: 8 LDS samples/thread -> branchless sort-8 -> wave 8th
    unsigned tb[8];
#pragma unroll
    for (int j = 0; j < 8; ++j) tb[j] = sad3_u8(slice_px[j * 1024 + st], Qme);
#define CEV(a, c) do { unsigned lo = min(tb[a], tb[c]); unsigned hi = max(tb[a], tb[c]); tb[a] = lo; tb[c] = hi; } while (0)
    CEV(0,1); CEV(2,3); CEV(4,5); CEV(6,7);
    CEV(0,2); CEV(1,3); CEV(4,6); CEV(5,7);
    CEV(1,2); CEV(5,6);
    CEV(0,4); CEV(1,5); CEV(2,6); CEV(3,7);
    CEV(2,4); CEV(3,5);
    CEV(1,2); CEV(3,4); CEV(5,6);
#undef CEV
#pragma unroll
    for (int off = 1; off < 64; off <<= 1) {
        unsigned ov[8];
#pragma unroll
        for (int k = 0; k < 8; ++k) ov[k] = (unsigned)__shfl_xor((int)tb[k], off, 64);
        unsigned w[8];
#pragma unroll
        for (int k = 0; k < 8; ++k) w[k] = min(tb[k], ov[7 - k]);
#define CEW(a, c) do { unsigned lo = min(w[a], w[c]); unsigned hi = max(w[a], w[c]); w[a] = lo; w[c] = hi; } while (0)
        CEW(0, 4); CEW(1, 5); CEW(2, 6); CEW(3, 7);
        CEW(0, 2); CEW(1, 3); CEW(4, 6); CEW(5, 7);
        CEW(0, 1); CEW(2, 3); CEW(4, 5); CEW(6, 7);
#undef CEW
#pragma unroll
        for (int k = 0; k < 8; ++k) tb[k] = w[k];
    }
    if (lane == 0) tau8[wid] = tb[7];   // exact 8th smallest of wave's 512
    __syncthreads();

    unsigned Qu[NQ], T6[NQ];
    int sbase[NQ];
#pragma unroll
    for (int q = 0; q < NQ; ++q) {
        Qu[q] = pk255(pool[q][0], pool[q][1], pool[q][2]);
        // min of two wave-8ths >= slice's true u8 8th; +6 covers both-side
        // quantization error -> provable superset of the fp32 top-8.
        T6[q] = min(tau8[2 * q], tau8[2 * q + 1]) + 6u;
        sbase[q] = q * (512 * SLOTS) + tid * SLOTS;
    }

    // ---- Phase B: branchless LDS-resident scan; masked slot writes
    int cq[NQ];
#pragma unroll
    for (int q = 0; q < NQ; ++q) cq[q] = 0;
#pragma unroll
    for (int it = 0; it < SLICE_U4 / 512; ++it) {
        const int idx = it * 512 + tid;
        const uint4 P = ((const uint4*)slice_px)[idx];
        const unsigned gbase = (unsigned)(sl * SLICE_PIX + idx * 4);
#define PXQ(PV, J)                                                            \
        do {                                                                  \
            _Pragma("unroll")                                                 \
            for (int q = 0; q < NQ; ++q) {                                    \
                const unsigned su = sad3_u8((PV), Qu[q]);                     \
                const bool hit = su <= T6[q];                                 \
                if (hit)                                                      \
                    slots[sbase[q] + min(cq[q], SLOTS - 1)] =                 \
                        (su << 16) | (gbase + (J));                           \
                cq[q] += hit;                                                 \
            }                                                                 \
        } while (0)
        PXQ(P.x, 0); PXQ(P.y, 1); PXQ(P.z, 2); PXQ(P.w, 3);
#undef PXQ
    }
#pragma unroll
    for (int q = 0; q < NQ; ++q) {
        if (cq[q] > SLOTS) over[q] = 1;     // rare; sticky (race benign)
    }
    __syncthreads();

    // ---- Phase C: fp32 exact top-8 per query; 2 waves per query
    {
        const int q    = wid >> 1;
        const int half = wid & 1;
        const float p0 = pool[q][0], p1 = pool[q][1], p2 = pool[q][2];
        float bv[8]; int bi[8];
#pragma unroll
        for (int k = 0; k < 8; ++k) { bv[k] = 3.0e38f; bi[k] = 0x7FFFFFFF; }
#define INSERT(SIM, PIX)                                                      \
        do {                                                                  \
            if (lessVI((SIM), (PIX), bv[7], bi[7])) {                         \
                bv[7] = (SIM); bi[7] = (PIX);                                 \
                _Pragma("unroll")                                             \
                for (int k = 7; k > 0; --k) {                                 \
                    if (lessVI(bv[k], bi[k], bv[k - 1], bi[k - 1])) {         \
                        float tv = bv[k]; bv[k] = bv[k - 1]; bv[k - 1] = tv;  \
                        int   ti = bi[k]; bi[k] = bi[k - 1]; bi[k - 1] = ti;  \
                    }                                                         \
                }                                                             \
            }                                                                 \
        } while (0)
        if (over[q]) {
            // exact fallback: full-slice fp32 scan (almost never taken)
            for (int p = half * 64 + lane; p < SLICE_PIX; p += 128) {
                const int gpix = sl * SLICE_PIX + p;
                const float sim = fabsf(img[gpix] - p0)
                                + fabsf(img[NPIX + gpix] - p1)
                                + fabsf(img[2 * NPIX + gpix] - p2);
                INSERT(sim, gpix);
            }
        } else {
            for (int e = half * 64 + lane; e < 512 * SLOTS; e += 128) {
                const unsigned v = slots[q * (512 * SLOTS) + e];
                if (v != 0xFFFFFFFFu) {
                    const int gpix = (int)(v & 0xFFFFu);
                    const float sim = fabsf(img[gpix] - p0)
                                    + fabsf(img[NPIX + gpix] - p1)
                                    + fabsf(img[2 * NPIX + gpix] - p2);
                    INSERT(sim, gpix);
                }
            }
        }
#undef INSERT
        // wave bitonic merge with (val, idx)
#pragma unroll
        for (int off = 1; off < 64; off <<= 1) {
            float ov[8]; int oi[8];
#pragma unroll
            for (int k = 0; k < 8; ++k) {
                ov[k] = __shfl_xor(bv[k], off, 64);
                oi[k] = __shfl_xor(bi[k], off, 64);
            }
            float w[8]; int wi[8];
#pragma unroll
            for (int k = 0; k < 8; ++k) {
                if (lessVI(bv[k], bi[k], ov[7 - k], oi[7 - k])) { w[k] = bv[k];     wi[k] = bi[k]; }
                else                                            { w[k] = ov[7 - k]; wi[k] = oi[7 - k]; }
            }
            CE8(w, wi, 0, 4); CE8(w, wi, 1, 5); CE8(w, wi, 2, 6); CE8(w, wi, 3, 7);
            CE8(w, wi, 0, 2); CE8(w, wi, 1, 3); CE8(w, wi, 4, 6); CE8(w, wi, 5, 7);
            CE8(w, wi, 0, 1); CE8(w, wi, 2, 3); CE8(w, wi, 4, 5); CE8(w, wi, 6, 7);
#pragma unroll
            for (int k = 0; k < 8; ++k) { bv[k] = w[k]; bi[k] = wi[k]; }
        }
        if (lane == 0) {
#pragma unroll
            for (int k = 0; k < 8; ++k) { mv[q][half][k] = bv[k]; mi[q][half][k] = bi[k]; }
        }
    }
    __syncthreads();

    // merge the two halves, write sorted 8 to ws[(mq*NSLICE + sl)*8 ..]
    if (st == 0) {
        float av[8], bv2[8], ov[8]; int ai[8], bi2[8], oi[8];
#pragma unroll
        for (int k = 0; k < 8; ++k) {
            av[k]  = mv[qi][0][k]; ai[k]  = mi[qi][0][k];
            bv2[k] = mv[qi][1][k]; bi2[k] = mi[qi][1][k];
        }
        MERGE8(av, ai, bv2, bi2, ov, oi);
        const int mq = b * LQ + qg * NQ + qi;
        float2* o = ws + (mq * NSLICE + sl) * 8;
#pragma unroll
        for (int k = 0; k < 8; ++k) {
            float2 e; e.x = ov[k]; e.y = __int_as_float(oi[k]);
            o[k] = e;
        }
    }
    __syncthreads();

    // ---- device-scope ticket: last arrival does the loss epilogue
    if (tid == 0) {
        __threadfence();
        const int t = atomicAdd(counter, 1);
        lastflag = ((t % NBLK) == (NBLK - 1)) ? 1 : 0;
    }
    __syncthreads();
    if (!lastflag) return;
    __threadfence();

    // epilogue: thread t -> (b2, l2); merge 8 sorted slice lists, min-dist
    {
        const int b2 = tid >> 7;
        const int l2 = tid & (LQ - 1);
        float v = 0.0f;
        if (l2 >= 1) {
            const int mq = b2 * LQ + (l2 - 1);
            const float2* base = ws + mq * (NSLICE * 8);
            float fv[8]; int fi[8];
#pragma unroll
            for (int k = 0; k < 8; ++k) {
                const float2 e = base[k];
                fv[k] = e.x; fi[k] = __float_as_int(e.y);
            }
#pragma unroll
            for (int s2 = 1; s2 < NSLICE; ++s2) {
                float av[8], ov[8]; int ai[8], oi[8];
#pragma unroll
                for (int k = 0; k < 8; ++k) {
                    const float2 e = base[s2 * 8 + k];
                    av[k] = e.x; ai[k] = __float_as_int(e.y);
                }
                MERGE8(fv, fi, av, ai, ov, oi);
#pragma unroll
                for (int k = 0; k < 8; ++k) { fv[k] = ov[k]; fi[k] = oi[k]; }
            }
            const float qx = pred[(b2 * LQ + l2) * 8 + 0];
            const float qy = pred[(b2 * LQ + l2) * 8 + 1];
            float best = 3.0e38f;
#pragma unroll
            for (int k = 0; k < 8; ++k) {
                const int id = fi[k];
                const float tx = (float)(id & (IMG - 1)) * (1.0f / IMG);
                const float ty = (float)(id >> 8)        * (1.0f / IMG);
                const float dx = qx - tx;
                const float dy = qy - ty;
                best = fminf(best, sqrtf(dx * dx + dy * dy));
            }
            v = best;
        }
        red[tid] = v;
        __syncthreads();
        for (int s = 256; s > 0; s >>= 1) {
            if (tid < s) red[tid] += red[tid + s];
            __syncthreads();
        }
        if (tid == 0) out[0] = red[0] * (1.0f / (BS * (LQ - 1)));
    }
}

extern "C" void kernel_launch(void* const* d_in, const int* in_sizes, int n_in,
                              void* d_out, int out_size, void* d_ws, size_t ws_size,
                              hipStream_t stream) {
    const float* pred = (const float*)d_in[0];   // (4,128,8) f32
    const float* imgs = (const float*)d_in[1];   // (4,3,256,256) f32
    float* out = (float*)d_out;                  // scalar f32

    int*    counter = (int*)d_ws;                // 4 B ticket
    float2* ws      = (float2*)((char*)d_ws + 256);  // 512*8*8 float2 = 256 KB

    hipMemsetAsync(counter, 0, 4, stream);
    hipLaunchKernelGGL(fused_kernel, dim3(NBLK), dim3(512), 0, stream,
                       pred, imgs, ws, counter, out);
}

// Round 10
// 61.382 us; speedup vs baseline: 2.2298x; 2.2298x over previous
//
#include <hip/hip_runtime.h>
#include <math.h>

#define BS 4
#define LQ 128
#define IMG 256
#define NPIX (IMG*IMG)
#define NCELL 4096
#define CAPC 24
#define OCAP 8192
#define CELLW 0.0625f
#define NBLKQ (BS*LQ)        // 512 query blocks

// ws byte offsets
#define WS_COUNTER 0
#define WS_OCNT    64
#define WS_WSQ     4096      // float2[512][8] = 32 KB
#define WS_GCNT    65536     // u32[4][4096]   = 64 KB
#define WS_OVER    131072    // float4[4][8192] = 512 KB
#define WS_CELLS   1048576   // float4[4][4096][24] = 6 MB

__device__ __forceinline__ bool lessVI(float v1, int i1, float v2, int i2) {
    return (v1 < v2) || (v1 == v2 && i1 < i2);
}

#define CE8(WV, WI, a, c)                                                     \
    do {                                                                      \
        if (lessVI((WV)[c], (WI)[c], (WV)[a], (WI)[a])) {                     \
            float tv_ = (WV)[a]; (WV)[a] = (WV)[c]; (WV)[c] = tv_;            \
            int   ti_ = (WI)[a]; (WI)[a] = (WI)[c]; (WI)[c] = ti_;            \
        }                                                                     \
    } while (0)

#define MERGE8(AV, AI, BV, BI, OV, OI)                                        \
    do {                                                                      \
        _Pragma("unroll")                                                     \
        for (int k_ = 0; k_ < 8; ++k_) {                                      \
            if (lessVI((AV)[k_], (AI)[k_], (BV)[7-k_], (BI)[7-k_])) {         \
                (OV)[k_] = (AV)[k_]; (OI)[k_] = (AI)[k_];                     \
            } else { (OV)[k_] = (BV)[7-k_]; (OI)[k_] = (BI)[7-k_]; }          \
        }                                                                     \
        CE8(OV, OI, 0, 4); CE8(OV, OI, 1, 5); CE8(OV, OI, 2, 6); CE8(OV, OI, 3, 7); \
        CE8(OV, OI, 0, 2); CE8(OV, OI, 1, 3); CE8(OV, OI, 4, 6); CE8(OV, OI, 5, 7); \
        CE8(OV, OI, 0, 1); CE8(OV, OI, 2, 3); CE8(OV, OI, 4, 5); CE8(OV, OI, 6, 7); \
    } while (0)

__device__ __forceinline__ int cell_of(float r, float g, float b) {
    // *16 is exact (exponent shift); (int) is floor for nonneg => exact cell
    const int cx = min((int)(r * 16.0f), 15);
    const int cy = min((int)(g * 16.0f), 15);
    const int cz = min((int)(b * 16.0f), 15);
    return cx | (cy << 4) | (cz << 8);
}

// 64 blocks (batch b = bid>>4, chunk = bid&15) x 256 threads.
// Counting-scatter 4096 px/chunk into per-(batch,cell) arrays (cap 24) with
// exact fp32 colors; beyond-cap pixels go to a per-batch overflow list.
__global__ __launch_bounds__(256)
void build_kernel(const float* __restrict__ imgs,
                  unsigned* __restrict__ gcnt,
                  float4* __restrict__ cells,
                  float4* __restrict__ overflow,
                  int* __restrict__ ocnt) {
    __shared__ unsigned lhist[NCELL];
    __shared__ unsigned lbase[NCELL];
    const int bid = blockIdx.x;
    const int b = bid >> 4;
    const int chunk = bid & 15;
    const int tid = threadIdx.x;
    const float* img = imgs + b * 3 * NPIX;
    const float4* i0 = (const float4*)img;
    const float4* i1 = (const float4*)(img + NPIX);
    const float4* i2 = (const float4*)(img + 2 * NPIX);

#pragma unroll
    for (int k = 0; k < NCELL / 256; ++k) lhist[tid + k * 256] = 0;
    __syncthreads();

    // phase 1: local histogram
#pragma unroll
    for (int i = 0; i < 4; ++i) {
        const int idx4 = chunk * 1024 + i * 256 + tid;
        const float4 r = i0[idx4];
        const float4 g = i1[idx4];
        const float4 bl = i2[idx4];
        atomicAdd(&lhist[cell_of(r.x, g.x, bl.x)], 1u);
        atomicAdd(&lhist[cell_of(r.y, g.y, bl.y)], 1u);
        atomicAdd(&lhist[cell_of(r.z, g.z, bl.z)], 1u);
        atomicAdd(&lhist[cell_of(r.w, g.w, bl.w)], 1u);
    }
    __syncthreads();

    // phase 2: reserve global ranges per nonzero cell; reset cursors
#pragma unroll
    for (int k = 0; k < NCELL / 256; ++k) {
        const int c = tid + k * 256;
        const unsigned h = lhist[c];
        lbase[c] = h ? atomicAdd(&gcnt[b * NCELL + c], h) : 0u;
    }
    __syncthreads();
#pragma unroll
    for (int k = 0; k < NCELL / 256; ++k) lhist[tid + k * 256] = 0;
    __syncthreads();

    // phase 3: scatter (cell arrays unordered -> fine, selection is
    // order-invariant lexicographic (val,idx))
#pragma unroll
    for (int i = 0; i < 4; ++i) {
        const int idx4 = chunk * 1024 + i * 256 + tid;
        const float4 r = i0[idx4];
        const float4 g = i1[idx4];
        const float4 bl = i2[idx4];
        const int pbase = idx4 * 4;
#define SCAT(RR, GG, BB, J)                                                   \
        do {                                                                  \
            const int c_ = cell_of(RR, GG, BB);                               \
            const unsigned lo_ = atomicAdd(&lhist[c_], 1u);                   \
            const unsigned slot_ = lbase[c_] + lo_;                           \
            float4 e_; e_.x = (RR); e_.y = (GG); e_.z = (BB);                 \
            e_.w = __int_as_float(pbase + (J));                               \
            if (slot_ < CAPC) {                                               \
                cells[(b * NCELL + c_) * CAPC + slot_] = e_;                  \
            } else {                                                          \
                const int o_ = atomicAdd(&ocnt[b], 1);                        \
                if (o_ < OCAP) overflow[b * OCAP + o_] = e_;                  \
            }                                                                 \
        } while (0)
        SCAT(r.x, g.x, bl.x, 0);
        SCAT(r.y, g.y, bl.y, 1);
        SCAT(r.z, g.z, bl.z, 2);
        SCAT(r.w, g.w, bl.w, 3);
#undef SCAT
    }
}

#define INSERT(SIM, PIX)                                                      \
    do {                                                                      \
        if (lessVI((SIM), (PIX), bv[7], bi[7])) {                             \
            bv[7] = (SIM); bi[7] = (PIX);                                     \
            _Pragma("unroll")                                                 \
            for (int k = 7; k > 0; --k) {                                     \
                if (lessVI(bv[k], bi[k], bv[k - 1], bi[k - 1])) {             \
                    float tv = bv[k]; bv[k] = bv[k - 1]; bv[k - 1] = tv;      \
                    int   ti = bi[k]; bi[k] = bi[k - 1]; bi[k - 1] = ti;      \
                }                                                             \
            }                                                                 \
        }                                                                     \
    } while (0)

#define WAVE_BITONIC()                                                        \
    do {                                                                      \
        _Pragma("unroll")                                                     \
        for (int off = 1; off < 64; off <<= 1) {                              \
            float ov[8]; int oi[8];                                           \
            _Pragma("unroll")                                                 \
            for (int k = 0; k < 8; ++k) {                                     \
                ov[k] = __shfl_xor(bv[k], off, 64);                           \
                oi[k] = __shfl_xor(bi[k], off, 64);                           \
            }                                                                 \
            float w[8]; int wi[8];                                            \
            _Pragma("unroll")                                                 \
            for (int k = 0; k < 8; ++k) {                                     \
                if (lessVI(bv[k], bi[k], ov[7 - k], oi[7 - k])) {             \
                    w[k] = bv[k]; wi[k] = bi[k];                              \
                } else { w[k] = ov[7 - k]; wi[k] = oi[7 - k]; }               \
            }                                                                 \
            CE8(w, wi, 0, 4); CE8(w, wi, 1, 5); CE8(w, wi, 2, 6); CE8(w, wi, 3, 7); \
            CE8(w, wi, 0, 2); CE8(w, wi, 1, 3); CE8(w, wi, 4, 6); CE8(w, wi, 5, 7); \
            CE8(w, wi, 0, 1); CE8(w, wi, 2, 3); CE8(w, wi, 4, 5); CE8(w, wi, 6, 7); \
            _Pragma("unroll")                                                 \
            for (int k = 0; k < 8; ++k) { bv[k] = w[k]; bi[k] = wi[k]; }      \
        }                                                                     \
    } while (0)

// 512 blocks x 256 threads: one block per query (b,l).
// Stage 1: exact scan of the 27-cell box around pooled color; per-lane lists
//          stay DISJOINT (bound S8 computed on a values-only copy).
// Stage 2: scan remaining cells with d_min <= S8 (usually none) + overflow.
// One final wave bitonic + cross-wave merge -> exact lexicographic top-8.
// Ticket: last block computes the loss.
__global__ __launch_bounds__(256)
void query_kernel(const float* __restrict__ pred,
                  const float* __restrict__ imgs,
                  const unsigned* __restrict__ gcnt,
                  const float4* __restrict__ cells,
                  const float4* __restrict__ overflow,
                  const int* __restrict__ ocnt,
                  float2* __restrict__ wsq,
                  int* __restrict__ counter,
                  float* __restrict__ out) {
    __shared__ float mvv[4][8];
    __shared__ int   mii[4][8];
    __shared__ float tau4[4];
    __shared__ int   lastflag;
    __shared__ float red[256];

    const int qid = blockIdx.x;
    const int b = qid >> 7;
    const int l = qid & (LQ - 1);
    const int tid = threadIdx.x;
    const int wid = tid >> 6;
    const int lane = tid & 63;

    // pooled color (reshape quirk: flat row n = l*BS + b of preds(bs*L,2))
    const int n  = l * BS + b;
    const int pb = n >> 7;
    const int pl = n & (LQ - 1);
    const float gx = pred[(pb * LQ + pl) * 8 + 0];
    const float gy = pred[(pb * LQ + pl) * 8 + 1];
    const int ix = (int)fminf(fmaxf(rintf(gx * 256.0f - 0.5f), 0.0f), 255.0f);
    const int iy = (int)fminf(fmaxf(rintf(gy * 256.0f - 0.5f), 0.0f), 255.0f);
    const float* img = imgs + b * 3 * NPIX;
    const int pc = iy * IMG + ix;
    const float c0 = img[pc];
    const float c1 = img[NPIX + pc];
    const float c2 = img[2 * NPIX + pc];
    const int qx = min((int)(c0 * 16.0f), 15);
    const int qy = min((int)(c1 * 16.0f), 15);
    const int qz = min((int)(c2 * 16.0f), 15);

    const unsigned* cnt_b = gcnt + b * NCELL;
    const float4*   cel_b = cells + b * NCELL * CAPC;

    float bv[8]; int bi[8];
#pragma unroll
    for (int k = 0; k < 8; ++k) { bv[k] = 3.0e38f; bi[k] = 0x7FFFFFFF; }

    // ---- Stage 1: 27-cell box, 9 threads per cell (per-lane disjoint)
    if (tid < 243) {
        const int ci = tid / 9;
        const int sub = tid % 9;
        const int cx = qx + (ci % 3) - 1;
        const int cy = qy + ((ci / 3) % 3) - 1;
        const int cz = qz + (ci / 9) - 1;
        if (cx >= 0 && cx < 16 && cy >= 0 && cy < 16 && cz >= 0 && cz < 16) {
            const int c = cx | (cy << 4) | (cz << 8);
            const int ce = min((int)cnt_b[c], CAPC);
            for (int e = sub; e < ce; e += 9) {
                const float4 E = cel_b[c * CAPC + e];
                const float sim = fabsf(E.x - c0) + fabsf(E.y - c1) + fabsf(E.z - c2);
                INSERT(sim, __float_as_int(E.w));
            }
        }
    }
    // S8 bound from a VALUES-ONLY copy (keeps bv/bi per-lane disjoint!)
    {
        float tv[8];
#pragma unroll
        for (int k = 0; k < 8; ++k) tv[k] = bv[k];
#pragma unroll
        for (int off = 1; off < 64; off <<= 1) {
            float ov[8];
#pragma unroll
            for (int k = 0; k < 8; ++k) ov[k] = __shfl_xor(tv[k], off, 64);
            float w[8];
#pragma unroll
            for (int k = 0; k < 8; ++k) w[k] = fminf(tv[k], ov[7 - k]);
#define CEW(a, c) do { float lo = fminf(w[a], w[c]); float hi = fmaxf(w[a], w[c]); w[a] = lo; w[c] = hi; } while (0)
            CEW(0, 4); CEW(1, 5); CEW(2, 6); CEW(3, 7);
            CEW(0, 2); CEW(1, 3); CEW(4, 6); CEW(5, 7);
            CEW(0, 1); CEW(2, 3); CEW(4, 5); CEW(6, 7);
#undef CEW
#pragma unroll
            for (int k = 0; k < 8; ++k) tv[k] = w[k];
        }
        if (lane == 0) tau4[wid] = tv[7];   // wave's 8th smallest (or 3e38)
    }
    __syncthreads();
    // each wave-8th is an upper bound on the block's true 8th (>=8 elems <=
    // it); min over waves = tightest available valid bound
    const float S8 = fminf(fminf(tau4[0], tau4[1]), fminf(tau4[2], tau4[3]));

    // ---- Stage 2: cells with d_min <= S8 outside the 27-box, + overflow
    {
        const int R = (S8 > 1.0f) ? 16 : min((int)(S8 * 16.0f) + 2, 16);
        const int side = 2 * R + 1;
        const int tot = side * side * side;
        for (int t2 = tid; t2 < tot; t2 += 256) {
            const int dx = t2 % side - R;
            const int dy = (t2 / side) % side - R;
            const int dz = t2 / (side * side) - R;
            if (dx >= -1 && dx <= 1 && dy >= -1 && dy <= 1 && dz >= -1 && dz <= 1)
                continue;   // already scanned in stage 1
            const int cx = qx + dx, cy = qy + dy, cz = qz + dz;
            if (cx < 0 || cx > 15 || cy < 0 || cy > 15 || cz < 0 || cz > 15)
                continue;
            // conservative fp32 lower bound on any pixel's sim in this cell
            const float lox = cx * CELLW, loy = cy * CELLW, loz = cz * CELLW;
            const float dmx = fmaxf(fmaxf(lox - c0, c0 - (lox + CELLW)), 0.0f);
            const float dmy = fmaxf(fmaxf(loy - c1, c1 - (loy + CELLW)), 0.0f);
            const float dmz = fmaxf(fmaxf(loz - c2, c2 - (loz + CELLW)), 0.0f);
            if (dmx + dmy + dmz > S8) continue;
            const int c = cx | (cy << 4) | (cz << 8);
            const int ce = min((int)cnt_b[c], CAPC);
            for (int e = 0; e < ce; ++e) {
                const float4 E = cel_b[c * CAPC + e];
                const float sim = fabsf(E.x - c0) + fabsf(E.y - c1) + fabsf(E.z - c2);
                INSERT(sim, __float_as_int(E.w));
            }
        }
        const int oc = min(ocnt[b], OCAP);
        for (int e = tid; e < oc; e += 256) {
            const float4 E = overflow[b * OCAP + e];
            const float sim = fabsf(E.x - c0) + fabsf(E.y - c1) + fabsf(E.z - c2);
            INSERT(sim, __float_as_int(E.w));
        }
    }

    // ---- single final reduction: wave bitonic + cross-wave merge
    WAVE_BITONIC();
    if (lane == 0) {
#pragma unroll
        for (int k = 0; k < 8; ++k) { mvv[wid][k] = bv[k]; mii[wid][k] = bi[k]; }
    }
    __syncthreads();
    if (tid == 0) {
        float a0[8], a1[8], a2[8], a3[8], m0[8], m1[8], f[8];
        int   x0[8], x1[8], x2[8], x3[8], y0[8], y1[8], z[8];
#pragma unroll
        for (int k = 0; k < 8; ++k) {
            a0[k] = mvv[0][k]; x0[k] = mii[0][k];
            a1[k] = mvv[1][k]; x1[k] = mii[1][k];
            a2[k] = mvv[2][k]; x2[k] = mii[2][k];
            a3[k] = mvv[3][k]; x3[k] = mii[3][k];
        }
        MERGE8(a0, x0, a1, x1, m0, y0);
        MERGE8(a2, x2, a3, x3, m1, y1);
        MERGE8(m0, y0, m1, y1, f, z);
        float2* o = wsq + qid * 8;
#pragma unroll
        for (int k = 0; k < 8; ++k) {
            float2 e; e.x = f[k]; e.y = __int_as_float(z[k]);
            o[k] = e;
        }
    }
    __syncthreads();

    // ---- device-scope ticket: last arrival computes the loss
    if (tid == 0) {
        __threadfence();
        const int t = atomicAdd(counter, 1);
        lastflag = ((t % NBLKQ) == (NBLKQ - 1)) ? 1 : 0;
    }
    __syncthreads();
    if (!lastflag) return;
    __threadfence();

    {
        float acc = 0.0f;
#pragma unroll
        for (int pp = 0; pp < 2; ++pp) {
            const int p = tid + pp * 256;
            const int b2 = p >> 7;
            const int l2 = p & (LQ - 1);
            if (l2 >= 1) {
                const int mq = b2 * LQ + (l2 - 1);
                const float2* base = wsq + mq * 8;
                const float qx2 = pred[(b2 * LQ + l2) * 8 + 0];
                const float qy2 = pred[(b2 * LQ + l2) * 8 + 1];
                float best = 3.0e38f;
#pragma unroll
                for (int k = 0; k < 8; ++k) {
                    const float2 e = base[k];
                    const int id = __float_as_int(e.y);
                    const float tx = (float)(id & (IMG - 1)) * (1.0f / IMG);
                    const float ty = (float)(id >> 8)        * (1.0f / IMG);
                    const float dx = qx2 - tx;
                    const float dy = qy2 - ty;
                    best = fminf(best, sqrtf(dx * dx + dy * dy));
                }
                acc += best;
            }
        }
        red[tid] = acc;
        __syncthreads();
        for (int s = 128; s > 0; s >>= 1) {
            if (tid < s) red[tid] += red[tid + s];
            __syncthreads();
        }
        if (tid == 0) out[0] = red[0] * (1.0f / (BS * (LQ - 1)));
    }
}

extern "C" void kernel_launch(void* const* d_in, const int* in_sizes, int n_in,
                              void* d_out, int out_size, void* d_ws, size_t ws_size,
                              hipStream_t stream) {
    const float* pred = (const float*)d_in[0];   // (4,128,8) f32
    const float* imgs = (const float*)d_in[1];   // (4,3,256,256) f32
    float* out = (float*)d_out;                  // scalar f32

    char* w = (char*)d_ws;
    int*      counter  = (int*)(w + WS_COUNTER);
    int*      ocnt     = (int*)(w + WS_OCNT);
    float2*   wsq      = (float2*)(w + WS_WSQ);
    unsigned* gcnt     = (unsigned*)(w + WS_GCNT);
    float4*   overflow = (float4*)(w + WS_OVER);
    float4*   cells    = (float4*)(w + WS_CELLS);

    // zero counter + ocnt + wsq + gcnt in one shot
    hipMemsetAsync(d_ws, 0, 131072, stream);
    hipLaunchKernelGGL(build_kernel, dim3(64), dim3(256), 0, stream,
                       imgs, gcnt, cells, overflow, ocnt);
    hipLaunchKernelGGL(query_kernel, dim3(NBLKQ), dim3(256), 0, stream,
                       pred, imgs, gcnt, cells, overflow, ocnt,
                       wsq, counter, out);
}